// Round 7
// baseline (36.414 us; speedup 1.0000x reference)
//
#include <hip/hip_runtime.h>

#define TOTAL 286
#define KG 32      // grid points per Euler angle
#define NM 11      // 2L-1
#define CIN 16
#define COUT 32
#define BB 8
#define DROW 16                  // padded n-columns (cols 11..15 always zero)
#define YPN (6 * 16 * DROW)      // 1536 floats

typedef float    v4f  __attribute__((ext_vector_type(4)));
typedef _Float16 v4h  __attribute__((ext_vector_type(4)));
// dword-aligned v4 for raw (unpadded) d-loads
typedef float    v4fu __attribute__((ext_vector_type(4), aligned(4)));

// Grid 512 = (b,o) x 2 q-halves; 1024 threads (16 waves); ONE q per wave.
// Register-lean (target <=64 VGPR -> 2 blocks/CU = 32 waves/CU): Yp is read from
// LDS inside the l-loop, offsets recomputed, single-q body. Cross-block max via
// int-atomicMax on d_out (valid: per-(b,o) max is positive; idempotent across
// replays; poison/memset int-compare below any positive float).
__global__ __launch_bounds__(1024, 8) void so3_fused(
    const float* __restrict__ x,    // [B, CIN, TOTAL]
    const float* __restrict__ w,    // [COUT, CIN, TOTAL]
    const float* __restrict__ d1,   // [KG, TOTAL]
    const float* __restrict__ d2,   // [KG, TOTAL]
    const float* __restrict__ ca1,  // [NM, KG]
    const float* __restrict__ cg1,  // [NM, KG]
    const float* __restrict__ ca2,  // [NM, KG]
    const float* __restrict__ cg2,  // [NM, KG]
    float* __restrict__ out)        // [B, COUT]
{
    __shared__ float ySm[288];
    __shared__ __align__(16) float Yp[YPN];
    __shared__ float redw[16];

    const int tid  = threadIdx.x;
    const int lane = tid & 63;
    const int wid  = tid >> 6;          // 0..15
    const int gid  = blockIdx.x;
    const int bo   = gid >> 1;
    const int half = gid & 1;
    const int b    = bo >> 5;
    const int o    = bo & 31;
    const int q    = half * 16 + wid;   // one q per wave

    // ---- y[i] = sum_c x[b,c,i] * w[o,c,i]
    if (tid < TOTAL) {
        const float* xp = x + b * CIN * TOTAL + tid;
        const float* wp = w + o * CIN * TOTAL + tid;
        float acc = 0.f;
        #pragma unroll
        for (int c = 0; c < CIN; ++c)
            acc = fmaf(xp[c * TOTAL], wp[c * TOTAL], acc);
        ySm[tid] = acc;
    }

    // ---- q-invariant MFMA fragments (layout verified rounds 3-6):
    // A[m][k]: (m=lane&15, k=4*(lane>>4)+i); B[k][n]: (k=4g+i, n=fr);
    // D[m][n]: (m=4g+j, n=fr) == B-frag -> register chaining between GEMMs.
    const int fr = lane & 15;
    const int g  = lane >> 4;
    v4h G1f[2], G2f[2], A1f[2], A2f[2];
    #pragma unroll
    for (int t = 0; t < 2; ++t) {
        #pragma unroll
        for (int i = 0; i < 4; ++i) {
            const int k = 4 * g + i;
            const int c = fr + 16 * t;
            const bool v = (k < NM);
            G1f[t][i] = (_Float16)(v ? cg1[k * KG + c] : 0.f);
            G2f[t][i] = (_Float16)(v ? cg2[k * KG + c] : 0.f);
            A1f[t][i] = (_Float16)(v ? ca1[k * KG + c] : 0.f);
            A2f[t][i] = (_Float16)(v ? ca2[k * KG + c] : 0.f);
        }
    }
    __syncthreads();   // ySm ready

    // ---- Yp[l][m][16]: zero-padded y (cols 11..15 and invalid (l,m,n) = 0)
    if (tid < 6 * 16 * 4) {
        const int gg = tid & 3;
        const int m  = (tid >> 2) & 15;
        const int l  = tid >> 6;
        v4f z = {0.f, 0.f, 0.f, 0.f};
        const int mp = m - 5;
        if (mp >= -l && mp <= l && gg < 3) {
            const int base = l * (4 * l * l - 1) / 3 + (2 * l + 1) * (l + mp) + l - 5;
            #pragma unroll
            for (int j = 0; j < 4; ++j) {
                const int n = 4 * gg + j, np = n - 5;
                if (np >= -l && np <= l) z[j] = ySm[base + n];
            }
        }
        *(v4f*)&Yp[(l * 16 + m) * DROW + 4 * gg] = z;
    }
    __syncthreads();   // Yp ready

    const float* d1q = d1 + q * TOTAL;
    const float* d2q = d2 + q * TOTAL;
    const v4f zero4 = {0.f, 0.f, 0.f, 0.f};

    // ---- Stage A: S[fr][4g+i] = sum_l Yp[l][fr][4g+i] * d[q, base_l + 4g+i]
    // Yp's zeros mask all invalid/garbage d lanes (garbage * 0 = 0).
    v4f s1 = zero4, s2 = zero4;
    const int mp = fr - 5;
    #pragma unroll
    for (int l = 0; l < 6; ++l) {
        const v4f yv = *(const v4f*)&Yp[(l * 16 + fr) * DROW + 4 * g];
        const bool valid = (mp >= -l && mp <= l);
        const int base = l * (4 * l * l - 1) / 3 + (2 * l + 1) * (l + mp) + l - 5;
        const int doff = valid ? base + 4 * g : 0;
        s1 += yv * (v4f)(*(const v4fu*)&d1q[doff]);
        s2 += yv * (v4f)(*(const v4fu*)&d2q[doff]);
    }
    v4h a1, a2;
    #pragma unroll
    for (int i = 0; i < 4; ++i) { a1[i] = (_Float16)s1[i]; a2[i] = (_Float16)s2[i]; }

    // ---- GEMM-B: T = S * G (K = n, padded to 16)
    v4f t1a = __builtin_amdgcn_mfma_f32_16x16x16f16(a1, G1f[0], zero4, 0, 0, 0);
    v4f t1b = __builtin_amdgcn_mfma_f32_16x16x16f16(a1, G1f[1], zero4, 0, 0, 0);
    v4f t2a = __builtin_amdgcn_mfma_f32_16x16x16f16(a2, G2f[0], zero4, 0, 0, 0);
    v4f t2b = __builtin_amdgcn_mfma_f32_16x16x16f16(a2, G2f[1], zero4, 0, 0, 0);
    v4h b1a, b1b, b2a, b2b;
    #pragma unroll
    for (int i = 0; i < 4; ++i) {
        b1a[i] = (_Float16)t1a[i]; b1b[i] = (_Float16)t1b[i];
        b2a[i] = (_Float16)t2a[i]; b2b[i] = (_Float16)t2b[i];
    }

    // ---- GEMM-C: resp = ca1^T*T1 + ca2^T*T2 (K = m, padded to 16)
    float lmax = -INFINITY;
    #pragma unroll
    for (int pt = 0; pt < 2; ++pt) {
        v4f acc0 = __builtin_amdgcn_mfma_f32_16x16x16f16(A2f[pt], b2a, zero4, 0, 0, 0);
        acc0     = __builtin_amdgcn_mfma_f32_16x16x16f16(A1f[pt], b1a, acc0, 0, 0, 0);
        v4f acc1 = __builtin_amdgcn_mfma_f32_16x16x16f16(A2f[pt], b2b, zero4, 0, 0, 0);
        acc1     = __builtin_amdgcn_mfma_f32_16x16x16f16(A1f[pt], b1b, acc1, 0, 0, 0);
        #pragma unroll
        for (int j = 0; j < 4; ++j) {
            lmax = fmaxf(lmax, acc0[j]);
            lmax = fmaxf(lmax, acc1[j]);
        }
    }

    // ---- reduction: wave shuffle, then across 16 waves, then global atomic
    #pragma unroll
    for (int off = 32; off > 0; off >>= 1)
        lmax = fmaxf(lmax, __shfl_xor(lmax, off, 64));
    if (lane == 0) redw[wid] = lmax;
    __syncthreads();
    if (tid == 0) {
        float v = redw[0];
        #pragma unroll
        for (int i = 1; i < 16; ++i) v = fmaxf(v, redw[i]);
        // int-ordered atomicMax == float max for positive values; poison/0 lose.
        atomicMax((int*)&out[bo], __float_as_int(v));
    }
}

extern "C" void kernel_launch(void* const* d_in, const int* in_sizes, int n_in,
                              void* d_out, int out_size, void* d_ws, size_t ws_size,
                              hipStream_t stream) {
    const float* x   = (const float*)d_in[0];
    const float* w   = (const float*)d_in[1];
    const float* d1  = (const float*)d_in[2];
    const float* d2  = (const float*)d_in[3];
    const float* ca1 = (const float*)d_in[4];
    const float* cg1 = (const float*)d_in[5];
    const float* ca2 = (const float*)d_in[6];
    const float* cg2 = (const float*)d_in[7];

    so3_fused<<<BB * COUT * 2, 1024, 0, stream>>>(
        x, w, d1, d2, ca1, cg1, ca2, cg2, (float*)d_out);
}

// Round 8
// 13.312 us; speedup vs baseline: 2.7354x; 2.7354x over previous
//
#include <hip/hip_runtime.h>

#define TOTAL 286
#define KG 32      // grid points per Euler angle
#define NM 11      // 2L-1
#define CIN 16
#define COUT 32
#define BB 8
#define DROW 16                  // padded n-columns (cols 11..15 always zero)
#define YPN (6 * 16 * DROW)      // 1536 floats

typedef float    v4f  __attribute__((ext_vector_type(4)));
typedef _Float16 v4h  __attribute__((ext_vector_type(4)));
// dword-aligned v4 for raw (unpadded) d-loads
typedef float    v4fu __attribute__((ext_vector_type(4), aligned(4)));

// Grid 512 = (b,o) x 2 q-halves; 512 threads (8 waves); wave owns q and q+8.
// __launch_bounds__(512,4): VGPR cap 128 (round 7 showed cap 64 => spill disaster),
// 2 blocks/CU so one block's prologue overlaps the other's q-loop.
// Cross-block combine: int atomicMax on d_out (positive maxima; poison is
// int-negative; idempotent across graph replays) — validated in round 7.
__global__ __launch_bounds__(512, 4) void so3_fused(
    const float* __restrict__ x,    // [B, CIN, TOTAL]
    const float* __restrict__ w,    // [COUT, CIN, TOTAL]
    const float* __restrict__ d1,   // [KG, TOTAL]
    const float* __restrict__ d2,   // [KG, TOTAL]
    const float* __restrict__ ca1,  // [NM, KG]
    const float* __restrict__ cg1,  // [NM, KG]
    const float* __restrict__ ca2,  // [NM, KG]
    const float* __restrict__ cg2,  // [NM, KG]
    float* __restrict__ out)        // [B, COUT]
{
    __shared__ float ySm[288];
    __shared__ __align__(16) float Yp[YPN];
    __shared__ float redw[8];

    const int tid  = threadIdx.x;
    const int lane = tid & 63;
    const int wid  = tid >> 6;          // 0..7
    const int gid  = blockIdx.x;
    const int bo   = gid >> 1;
    const int half = gid & 1;
    const int b    = bo >> 5;
    const int o    = bo & 31;

    // ---- y[i] = sum_c x[b,c,i] * w[o,c,i]
    if (tid < TOTAL) {
        const float* xp = x + b * CIN * TOTAL + tid;
        const float* wp = w + o * CIN * TOTAL + tid;
        float acc = 0.f;
        #pragma unroll
        for (int c = 0; c < CIN; ++c)
            acc = fmaf(xp[c * TOTAL], wp[c * TOTAL], acc);
        ySm[tid] = acc;
    }

    // ---- q-invariant MFMA fragments (layout verified rounds 3-7):
    // A[m][k]: (m=lane&15, k=4*(lane>>4)+i); B[k][n]: (k=4g+i, n=fr);
    // D[m][n]: (m=4g+j, n=fr) == B-frag -> register chaining between GEMMs.
    const int fr = lane & 15;
    const int g  = lane >> 4;
    v4h G1f[2], G2f[2], A1f[2], A2f[2];
    #pragma unroll
    for (int t = 0; t < 2; ++t) {
        #pragma unroll
        for (int i = 0; i < 4; ++i) {
            const int k = 4 * g + i;
            const int c = fr + 16 * t;
            const bool v = (k < NM);
            G1f[t][i] = (_Float16)(v ? cg1[k * KG + c] : 0.f);
            G2f[t][i] = (_Float16)(v ? cg2[k * KG + c] : 0.f);
            A1f[t][i] = (_Float16)(v ? ca1[k * KG + c] : 0.f);
            A2f[t][i] = (_Float16)(v ? ca2[k * KG + c] : 0.f);
        }
    }
    __syncthreads();   // ySm ready

    // ---- Yp[l][m][16]: zero-padded y (cols 11..15 and invalid (l,m,n) = 0)
    if (tid < 6 * 16 * 4) {
        const int gg = tid & 3;
        const int m  = (tid >> 2) & 15;
        const int l  = tid >> 6;
        v4f z = {0.f, 0.f, 0.f, 0.f};
        const int mp = m - 5;
        if (mp >= -l && mp <= l && gg < 3) {
            const int base = l * (4 * l * l - 1) / 3 + (2 * l + 1) * (l + mp) + l - 5;
            #pragma unroll
            for (int j = 0; j < 4; ++j) {
                const int n = 4 * gg + j, np = n - 5;
                if (np >= -l && np <= l) z[j] = ySm[base + n];
            }
        }
        *(v4f*)&Yp[(l * 16 + m) * DROW + 4 * gg] = z;
    }
    __syncthreads();   // Yp ready — no more barriers until the final reduce

    const v4f zero4 = {0.f, 0.f, 0.f, 0.f};
    const int mp = fr - 5;
    float lmax = -INFINITY;

    #pragma unroll
    for (int qi = 0; qi < 2; ++qi) {
        const int q = half * 16 + wid + 8 * qi;
        const float* d1q = d1 + q * TOTAL;
        const float* d2q = d2 + q * TOTAL;

        // ---- Stage A: S[fr][4g+i] = sum_l Yp[l][fr][4g+i] * d[q, base_l + 4g+i]
        // Yp's zeros mask all invalid/garbage d lanes (garbage * 0 = 0).
        v4f s1 = zero4, s2 = zero4;
        #pragma unroll
        for (int l = 0; l < 6; ++l) {
            const v4f yv = *(const v4f*)&Yp[(l * 16 + fr) * DROW + 4 * g];
            const bool valid = (mp >= -l && mp <= l);
            const int base = l * (4 * l * l - 1) / 3 + (2 * l + 1) * (l + mp) + l - 5;
            const int doff = valid ? base + 4 * g : 0;
            s1 += yv * (v4f)(*(const v4fu*)&d1q[doff]);
            s2 += yv * (v4f)(*(const v4fu*)&d2q[doff]);
        }
        v4h a1, a2;
        #pragma unroll
        for (int i = 0; i < 4; ++i) { a1[i] = (_Float16)s1[i]; a2[i] = (_Float16)s2[i]; }

        // ---- GEMM-B: T = S * G (K = n, padded to 16)
        v4f t1a = __builtin_amdgcn_mfma_f32_16x16x16f16(a1, G1f[0], zero4, 0, 0, 0);
        v4f t1b = __builtin_amdgcn_mfma_f32_16x16x16f16(a1, G1f[1], zero4, 0, 0, 0);
        v4f t2a = __builtin_amdgcn_mfma_f32_16x16x16f16(a2, G2f[0], zero4, 0, 0, 0);
        v4f t2b = __builtin_amdgcn_mfma_f32_16x16x16f16(a2, G2f[1], zero4, 0, 0, 0);
        v4h b1a, b1b, b2a, b2b;
        #pragma unroll
        for (int i = 0; i < 4; ++i) {
            b1a[i] = (_Float16)t1a[i]; b1b[i] = (_Float16)t1b[i];
            b2a[i] = (_Float16)t2a[i]; b2b[i] = (_Float16)t2b[i];
        }

        // ---- GEMM-C: resp = ca1^T*T1 + ca2^T*T2 (K = m, padded to 16)
        #pragma unroll
        for (int pt = 0; pt < 2; ++pt) {
            v4f acc0 = __builtin_amdgcn_mfma_f32_16x16x16f16(A2f[pt], b2a, zero4, 0, 0, 0);
            acc0     = __builtin_amdgcn_mfma_f32_16x16x16f16(A1f[pt], b1a, acc0, 0, 0, 0);
            v4f acc1 = __builtin_amdgcn_mfma_f32_16x16x16f16(A2f[pt], b2b, zero4, 0, 0, 0);
            acc1     = __builtin_amdgcn_mfma_f32_16x16x16f16(A1f[pt], b1b, acc1, 0, 0, 0);
            #pragma unroll
            for (int j = 0; j < 4; ++j) {
                lmax = fmaxf(lmax, acc0[j]);
                lmax = fmaxf(lmax, acc1[j]);
            }
        }
    }

    // ---- reduction: wave shuffle, across 8 waves, then global int-atomicMax
    #pragma unroll
    for (int off = 32; off > 0; off >>= 1)
        lmax = fmaxf(lmax, __shfl_xor(lmax, off, 64));
    if (lane == 0) redw[wid] = lmax;
    __syncthreads();
    if (tid == 0) {
        float v = redw[0];
        #pragma unroll
        for (int i = 1; i < 8; ++i) v = fmaxf(v, redw[i]);
        atomicMax((int*)&out[bo], __float_as_int(v));
    }
}

extern "C" void kernel_launch(void* const* d_in, const int* in_sizes, int n_in,
                              void* d_out, int out_size, void* d_ws, size_t ws_size,
                              hipStream_t stream) {
    const float* x   = (const float*)d_in[0];
    const float* w   = (const float*)d_in[1];
    const float* d1  = (const float*)d_in[2];
    const float* d2  = (const float*)d_in[3];
    const float* ca1 = (const float*)d_in[4];
    const float* cg1 = (const float*)d_in[5];
    const float* ca2 = (const float*)d_in[6];
    const float* cg2 = (const float*)d_in[7];

    so3_fused<<<BB * COUT * 2, 512, 0, stream>>>(
        x, w, d1, d2, ca1, cg1, ca2, cg2, (float*)d_out);
}